// Round 1
// baseline (343.323 us; speedup 1.0000x reference)
//
#include <hip/hip_runtime.h>

#define B_ 4
#define T_ 1024
#define D_ 256
#define O_ 256
#define NC 32   // chunks along T
#define CL 32   // chunk length (NC*CL == T_)

typedef float v4f __attribute__((ext_vector_type(4)));  // nontemporal-compatible

// ---------------- Kernel A: per-chunk sums S[b,c,d] ----------------
__global__ __launch_bounds__(256) void chunk_sums(const float* __restrict__ x,
                                                  float* __restrict__ S) {
    const int d  = threadIdx.x;          // 0..255
    const int bc = blockIdx.x;           // b*NC + c
    const int b  = bc / NC;
    const int c  = bc % NC;
    const float* xp = x + ((size_t)b * T_ + (size_t)c * CL) * D_ + d;
    float s = 0.f;
#pragma unroll
    for (int i = 0; i < CL; ++i) s += xp[(size_t)i * D_];
    S[((size_t)b * NC + c) * D_ + d] = s;
}

// ---------------- Kernel B: cm[b,t,d] = cumsum(x)/(t+1) ----------------
__global__ __launch_bounds__(256) void cumsum_mean(const float* __restrict__ x,
                                                   const float* __restrict__ S,
                                                   float* __restrict__ cm) {
    const int d  = threadIdx.x;
    const int bc = blockIdx.x;
    const int b  = bc / NC;
    const int c  = bc % NC;
    // Masked full-unroll: all 32 loads independent & in flight, one latency.
    float off = 0.f;
#pragma unroll
    for (int cc = 0; cc < NC; ++cc) {
        const float v = S[((size_t)b * NC + cc) * D_ + d];
        off += (cc < c) ? v : 0.f;
    }
    const float* xp = x  + ((size_t)b * T_ + (size_t)c * CL) * D_ + d;
    float*       cp = cm + ((size_t)b * T_ + (size_t)c * CL) * D_ + d;
    float run = off;
#pragma unroll 4
    for (int i = 0; i < CL; ++i) {
        run += xp[(size_t)i * D_];
        const int t = c * CL + i;
        cp[(size_t)i * D_] = run / (float)(t + 1);   // IEEE divide, matches ref
    }
}

// ---------------- Kernel C: out[b,t,:] = cm[b,t,:] @ W[t] ----------------
// One block per t (grid=1024, 4 blocks/CU). Wave dq streams the CONTIGUOUS
// 64 KB slab W[t][dq*64 .. dq*64+63][:] (8-deep double-buffered v4f pipeline),
// accumulating partial dot products for its 64 d's. 4-way LDS reduction at the
// end. 16 waves/CU (4/SIMD, max occupancy at ~110 VGPR) vs the previous
// 1 wave/SIMD — 4x the outstanding-load concurrency for HBM latency hiding.
__global__ __launch_bounds__(256) void gemm_t(const float* __restrict__ cm,
                                              const float* __restrict__ W,
                                              float* __restrict__ out) {
    const int t   = blockIdx.x;          // 0..T_-1
    const int tid = threadIdx.x;
    const int dq  = tid >> 6;            // d-quarter (== wave id), 0..3
    const int oq  = tid & 63;            // o-quad, o = oq*4

    __shared__ float cml[D_][4];         // [d][b], 4 KB; broadcast b128 reads
    __shared__ v4f   part[4][4][64];     // [dq][b][oq], 16 KB; lane-contiguous

    // Stage cm[:, t, :] (coalesced over d for each b)
#pragma unroll
    for (int b = 0; b < 4; ++b)
        cml[tid][b] = cm[((size_t)b * T_ + t) * D_ + tid];
    __syncthreads();

    const v4f* Wp = (const v4f*)(W + ((size_t)t * D_ + (size_t)dq * 64) * O_) + oq;

    v4f a0 = (v4f)(0.f), a1 = (v4f)(0.f), a2 = (v4f)(0.f), a3 = (v4f)(0.f);

    v4f w[16];
    // preload first half (local rows 0..7)
#pragma unroll
    for (int j = 0; j < 8; ++j)
        w[j] = __builtin_nontemporal_load(Wp + (size_t)j * (O_ / 4));

#pragma unroll 1
    for (int dd = 0; dd < 64; dd += 16) {
        // load second half (rows dd+8 .. dd+15)
#pragma unroll
        for (int j = 0; j < 8; ++j)
            w[8 + j] = __builtin_nontemporal_load(Wp + (size_t)(dd + 8 + j) * (O_ / 4));
        // compute first half
#pragma unroll
        for (int j = 0; j < 8; ++j) {
            const v4f c4 = *(const v4f*)cml[dq * 64 + dd + j];
            a0 += c4.x * w[j]; a1 += c4.y * w[j]; a2 += c4.z * w[j]; a3 += c4.w * w[j];
        }
        // load next first half (rows dd+16 .. dd+23)
        if (dd + 16 < 64) {
#pragma unroll
            for (int j = 0; j < 8; ++j)
                w[j] = __builtin_nontemporal_load(Wp + (size_t)(dd + 16 + j) * (O_ / 4));
        }
        // compute second half
#pragma unroll
        for (int j = 0; j < 8; ++j) {
            const v4f c4 = *(const v4f*)cml[dq * 64 + dd + 8 + j];
            a0 += c4.x * w[8 + j]; a1 += c4.y * w[8 + j];
            a2 += c4.z * w[8 + j]; a3 += c4.w * w[8 + j];
        }
    }

    // 4-way cross-wave reduction over d-quarters.
    // Layout [dq][b][oq]: consecutive lanes -> consecutive 16 B, conflict-free.
    part[dq][0][oq] = a0;
    part[dq][1][oq] = a1;
    part[dq][2][oq] = a2;
    part[dq][3][oq] = a3;
    __syncthreads();

    if (dq == 0) {
#pragma unroll
        for (int b = 0; b < 4; ++b) {
            v4f r = part[0][b][oq] + part[1][b][oq] + part[2][b][oq] + part[3][b][oq];
            __builtin_nontemporal_store(
                r, (v4f*)&out[((size_t)b * T_ + t) * O_ + (size_t)oq * 4]);
        }
    }
}

extern "C" void kernel_launch(void* const* d_in, const int* in_sizes, int n_in,
                              void* d_out, int out_size, void* d_ws, size_t ws_size,
                              hipStream_t stream) {
    const float* x = (const float*)d_in[0];   // (B,T,D) f32
    const float* W = (const float*)d_in[1];   // (T,D,O) f32
    float* out = (float*)d_out;               // (B,T,O) f32

    float* cm = (float*)d_ws;                        // B*T*D floats = 4 MB
    float* S  = (float*)d_ws + (size_t)B_ * T_ * D_; // B*NC*D floats = 128 KB

    chunk_sums <<<B_ * NC, 256, 0, stream>>>(x, S);
    cumsum_mean<<<B_ * NC, 256, 0, stream>>>(x, S, cm);
    gemm_t     <<<T_,      256, 0, stream>>>(cm, W, out);
}